// Round 5
// baseline (109.521 us; speedup 1.0000x reference)
//
#include <hip/hip_runtime.h>
#include <math.h>

// SplatCondenseNet fused tree pooling — wave-owns-rows float2 layout.
// Block = 512 threads (8 waves) = one 64-leaf L6 subtree.
// Wave wid owns x rows 8*wid..8*wid+7; lane owns cols 2l,2l+1 (float2).
// Per-thread live set ~45 regs -> fits 64 unified VGPRs (launch_bounds 512,8)
// -> 32 waves/CU and no AGPR spill traffic (round-4: 96-reg unified alloc
// capped occupancy at 65%).
// Every global access is one contiguous 512B segment per wave instruction.
// L1/L2/L3: wave-local (full-wave butterfly reductions for scores).
// L4 (wave pairs) / L5 (wave quads) / L6 (all 8 waves): one LDS exchange,
// 2 barriers total. All outputs stored non-temporally (write-once).
//
// Output layout (rows of 128 fp32, concat of layers 1..6):
//   L1 rows [0, 262144)  L2 [262144, 393216)  L3 [393216, 458752)
//   L4 [458752, 491520)  L5 [491520, 507904)  L6 [507904, 516096)

static constexpr size_t O1 = 0;
static constexpr size_t O2 = 262144ull * 128;
static constexpr size_t O3 = 393216ull * 128;
static constexpr size_t O4 = 458752ull * 128;
static constexpr size_t O5 = 491520ull * 128;
static constexpr size_t O6 = 507904ull * 128;

#define TPB 512

typedef float f2v __attribute__((ext_vector_type(2)));

__device__ __forceinline__ f2v f2add(f2v a, f2v b) { return a + b; }
__device__ __forceinline__ f2v f2mul(f2v a, float s) { return a * s; }
__device__ __forceinline__ f2v f2fma(f2v a, float s, f2v c) {
  f2v r;
  r.x = fmaf(a.x, s, c.x);
  r.y = fmaf(a.y, s, c.y);
  return r;
}
__device__ __forceinline__ void st_nt_f2(float* p, f2v v) {
  __builtin_nontemporal_store(v, (f2v*)p);
}
// sum across all 64 lanes (butterfly; every lane gets the result)
__device__ __forceinline__ float wave_sum(float p) {
#pragma unroll
  for (int off = 32; off > 0; off >>= 1) p += __shfl_xor(p, off, 64);
  return p;
}

template <int N>
__device__ __forceinline__ void softmax_n(const float* s, float* wt) {
  float m = s[0];
#pragma unroll
  for (int i = 1; i < N; ++i) m = fmaxf(m, s[i]);
  float sum = 0.f;
#pragma unroll
  for (int i = 0; i < N; ++i) {
    wt[i] = __expf(s[i] - m);
    sum += wt[i];
  }
  const float inv = 1.f / sum;
#pragma unroll
  for (int i = 0; i < N; ++i) wt[i] *= inv;
}

__global__ __launch_bounds__(TPB, 8) void splat_fused(
    const float* __restrict__ x0, const float* __restrict__ w,
    float* __restrict__ out) {
  // scores: s4 [0..31], s5 [32..47], s6 [48..55]
  __shared__ float ssc[56];
  __shared__ float pb4[8][128];  // L4 per-wave partials
  __shared__ float pb5[8][128];  // L5 per-wave partials
  __shared__ float pb6[8][128];  // L6 per-wave partials

  const int tid = threadIdx.x;
  const int wid = tid >> 6;   // wave 0..7: owns x rows 8*wid..8*wid+7
  const int lane = tid & 63;  // owns cols 2*lane, 2*lane+1
  const int c0 = lane << 1;
  const size_t b = blockIdx.x;
  const float scale = 0.08838834764831845f;  // 128^-0.5

  f2v qw = *(const f2v*)(w + c0);

  // ---- load 8 x float2 (one 512B segment per wave instruction) ----
  f2v xr[8];
  {
    const float* xb = x0 + b * 8192 + (size_t)(wid * 8) * 128 + c0;
#pragma unroll
    for (int r = 0; r < 8; ++r) xr[r] = *(const f2v*)(xb + r * 128);
  }

  // ---- L3 (group == wave): attention over x rows 8w..8w+7 ----
  f2v l3;
  {
    float s3[8];
#pragma unroll
    for (int r = 0; r < 8; ++r)
      s3[r] = wave_sum(xr[r].x * qw.x + xr[r].y * qw.y) * scale;
    float wt[8];
    softmax_n<8>(s3, wt);
    l3 = f2mul(xr[0], wt[0]);
#pragma unroll
    for (int r = 1; r < 8; ++r) l3 = f2fma(xr[r], wt[r], l3);
    st_nt_f2(out + O3 + (b * 8 + wid) * 128 + c0, l3);
  }

  // ---- L1: mean pairs (consumes xr) ----
  f2v l1[4];
#pragma unroll
  for (int j = 0; j < 4; ++j)
    l1[j] = f2mul(f2add(xr[2 * j], xr[2 * j + 1]), 0.5f);
  {
    float* g = out + O1 + (b * 32 + wid * 4) * 128 + c0;
#pragma unroll
    for (int j = 0; j < 4; ++j) st_nt_f2(g + j * 128, l1[j]);
  }

  // ---- L2: mean pairs of L1 ----
  f2v l2[2];
#pragma unroll
  for (int j = 0; j < 2; ++j)
    l2[j] = f2mul(f2add(l1[2 * j], l1[2 * j + 1]), 0.5f);
  {
    float* g = out + O2 + (b * 16 + wid * 2) * 128 + c0;
#pragma unroll
    for (int j = 0; j < 2; ++j) st_nt_f2(g + j * 128, l2[j]);
  }

  // ---- L4/L5/L6 scores -> LDS ----
  {
#pragma unroll
    for (int j = 0; j < 4; ++j) {
      const float s4 = wave_sum(l1[j].x * qw.x + l1[j].y * qw.y) * scale;
      if (lane == 0) ssc[wid * 4 + j] = s4;
    }
#pragma unroll
    for (int j = 0; j < 2; ++j) {
      const float s5 = wave_sum(l2[j].x * qw.x + l2[j].y * qw.y) * scale;
      if (lane == 0) ssc[32 + wid * 2 + j] = s5;
    }
    const float s6 = wave_sum(l3.x * qw.x + l3.y * qw.y) * scale;
    if (lane == 0) ssc[48 + wid] = s6;
  }
  __syncthreads();

  // ---- partial weighted sums -> LDS ----
  {
    float wt4[8];
    softmax_n<8>(ssc + (wid >> 1) * 8, wt4);  // L4 group = wave pair
    const int b4 = (wid & 1) * 4;             // my l1 rows within group
    f2v p4 = f2mul(l1[0], wt4[b4]);
#pragma unroll
    for (int j = 1; j < 4; ++j) p4 = f2fma(l1[j], wt4[b4 + j], p4);
    *(f2v*)(&pb4[wid][c0]) = p4;

    float wt5[8];
    softmax_n<8>(ssc + 32 + (wid >> 2) * 8, wt5);  // L5 group = wave quad
    const int b5 = (wid & 3) * 2;
    const f2v p5 = f2fma(l2[1], wt5[b5 + 1], f2mul(l2[0], wt5[b5]));
    *(f2v*)(&pb5[wid][c0]) = p5;

    float wt6[8];
    softmax_n<8>(ssc + 48, wt6);  // L6 group = all 8 waves
    *(f2v*)(&pb6[wid][c0]) = f2mul(l3, wt6[wid]);
  }
  __syncthreads();

  // ---- combine + store L4 (4 rows), L5 (2 rows), L6 (1 row) ----
  if (wid < 4) {
    const f2v v = f2add(*(const f2v*)(&pb4[2 * wid][c0]),
                        *(const f2v*)(&pb4[2 * wid + 1][c0]));
    st_nt_f2(out + O4 + (b * 4 + wid) * 128 + c0, v);
  } else if (wid < 6) {
    const int m = wid - 4;
    f2v v = f2add(*(const f2v*)(&pb5[4 * m][c0]),
                  *(const f2v*)(&pb5[4 * m + 1][c0]));
    v = f2add(v, *(const f2v*)(&pb5[4 * m + 2][c0]));
    v = f2add(v, *(const f2v*)(&pb5[4 * m + 3][c0]));
    st_nt_f2(out + O5 + (b * 2 + m) * 128 + c0, v);
  } else if (wid == 6) {
    f2v v = *(const f2v*)(&pb6[0][c0]);
#pragma unroll
    for (int s = 1; s < 8; ++s) v = f2add(v, *(const f2v*)(&pb6[s][c0]));
    st_nt_f2(out + O6 + b * 128 + c0, v);
  }
}

extern "C" void kernel_launch(void* const* d_in, const int* in_sizes, int n_in,
                              void* d_out, int out_size, void* d_ws,
                              size_t ws_size, hipStream_t stream) {
  const float* x0 = (const float*)d_in[0];
  const float* w = (const float*)d_in[1];
  float* out = (float*)d_out;
  const int n_leaves = in_sizes[0] / 128;  // 524288
  const int blocks = n_leaves / 64;        // 8192
  splat_fused<<<blocks, TPB, 0, stream>>>(x0, w, out);
}

// Round 6
// 96.505 us; speedup vs baseline: 1.1349x; 1.1349x over previous
//
#include <hip/hip_runtime.h>
#include <math.h>

// SplatCondenseNet fused tree pooling — register-resident, float4 fragments
// (round-4 structure) + tight register budget.
// Each block owns 64 consecutive leaves (one full L6 subtree).
// Thread layout: h = tid>>5 (slice 0..7) owns x rows 8h..8h+7 of the tile;
// cg = tid&31 owns columns 4cg..4cg+3 (float4 fragment).
//
// __launch_bounds__(256, 7): cap unified VGPR+AGPR at ~73/wave. Round-4's
// loose cap let the allocator pick ~96 unified regs (36 arch VGPR + ~60 AGPR,
// occupancy 65%). True peak live set ~60 regs -> 73 fits w/o scratch spill,
// lifting occupancy to ~28 waves/CU (87%).
// float2 experiment (round 5) REGRESSED: 8B/lane NT stores amplified
// WRITE_SIZE 258->389 MB. Keep 16B/lane float4 + NT stores.
//
// Output layout (rows of 128 fp32, concat of layers 1..6):
//   L1 rows [0, 262144)  L2 [262144, 393216)  L3 [393216, 458752)
//   L4 [458752, 491520)  L5 [491520, 507904)  L6 [507904, 516096)

static constexpr size_t O1 = 0;
static constexpr size_t O2 = 262144ull * 128;
static constexpr size_t O3 = 393216ull * 128;
static constexpr size_t O4 = 458752ull * 128;
static constexpr size_t O5 = 491520ull * 128;
static constexpr size_t O6 = 507904ull * 128;

#define TPB 256

typedef float f4v __attribute__((ext_vector_type(4)));

__device__ __forceinline__ float4 f4add(float4 a, float4 b) {
  return make_float4(a.x + b.x, a.y + b.y, a.z + b.z, a.w + b.w);
}
__device__ __forceinline__ float4 f4mul(float4 a, float s) {
  return make_float4(a.x * s, a.y * s, a.z * s, a.w * s);
}
__device__ __forceinline__ float4 f4fma(float4 a, float s, float4 c) {
  return make_float4(fmaf(a.x, s, c.x), fmaf(a.y, s, c.y), fmaf(a.z, s, c.z),
                     fmaf(a.w, s, c.w));
}
__device__ __forceinline__ float f4dot(float4 a, float4 b) {
  return a.x * b.x + a.y * b.y + a.z * b.z + a.w * b.w;
}
__device__ __forceinline__ void st_nt_f4(float* p, float4 v) {
  f4v t;
  t.x = v.x; t.y = v.y; t.z = v.z; t.w = v.w;
  __builtin_nontemporal_store(t, (f4v*)p);
}
__device__ __forceinline__ void st_nt_f1(float* p, float v) {
  __builtin_nontemporal_store(v, p);
}
// sum across the 32-lane slice (lanes 0..31 or 32..63 of a wave)
__device__ __forceinline__ float slice_sum(float p) {
#pragma unroll
  for (int off = 16; off > 0; off >>= 1) p += __shfl_xor(p, off, 64);
  return p;
}

template <int N>
__device__ __forceinline__ void softmax_n(const float* s, float* wt) {
  float m = s[0];
#pragma unroll
  for (int i = 1; i < N; ++i) m = fmaxf(m, s[i]);
  float sum = 0.f;
#pragma unroll
  for (int i = 0; i < N; ++i) {
    wt[i] = __expf(s[i] - m);
    sum += wt[i];
  }
  const float inv = 1.f / sum;
#pragma unroll
  for (int i = 0; i < N; ++i) wt[i] *= inv;
}

__global__ __launch_bounds__(TPB, 7) void splat_fused(
    const float* __restrict__ x0, const float* __restrict__ w,
    float* __restrict__ out) {
  __shared__ float ssc[24];      // L5 scores [0..15], L6 scores [16..23]
  __shared__ float pb5[8][128];  // L5 per-slice partials
  __shared__ float pb6[8][128];  // L6 per-slice partials

  const int tid = threadIdx.x;
  const int h = tid >> 5;   // slice: owns x rows 8h..8h+7
  const int cg = tid & 31;  // column group
  const int c0 = cg << 2;
  const size_t b = blockIdx.x;
  const float scale = 0.08838834764831845f;  // 128^-0.5

  const float4 wv = *(const float4*)(w + c0);

  // ---- load 8 x float4 (coalesced, cached) ----
  float4 xr[8];
  {
    const float* xb = x0 + b * 8192 + (size_t)(h * 8) * 128 + c0;
#pragma unroll
    for (int r = 0; r < 8; ++r) xr[r] = *(const float4*)(xb + r * 128);
  }

  // ---- L3 FIRST (while xr is hot): attention over x rows 8h..8h+7 ----
  float4 l3;
  {
    float s3[8];
#pragma unroll
    for (int r = 0; r < 8; ++r) s3[r] = slice_sum(f4dot(xr[r], wv)) * scale;
    float wt[8];
    softmax_n<8>(s3, wt);
    l3 = f4mul(xr[0], wt[0]);
#pragma unroll
    for (int r = 1; r < 8; ++r) l3 = f4fma(xr[r], wt[r], l3);
    st_nt_f4(out + O3 + (b * 8 + h) * 128 + c0, l3);
  }

  // ---- L1: mean pairs (consumes xr; xr dead after this) ----
  float4 l1[4];
#pragma unroll
  for (int j = 0; j < 4; ++j)
    l1[j] = f4mul(f4add(xr[2 * j], xr[2 * j + 1]), 0.5f);
  {
    float* g = out + O1 + (b * 32 + h * 4) * 128 + c0;
#pragma unroll
    for (int j = 0; j < 4; ++j) st_nt_f4(g + j * 128, l1[j]);
  }

  // ---- L2: mean pairs of L1 ----
  float4 l2[2];
#pragma unroll
  for (int j = 0; j < 2; ++j)
    l2[j] = f4mul(f4add(l1[2 * j], l1[2 * j + 1]), 0.5f);
  {
    float* g = out + O2 + (b * 16 + h * 2) * 128 + c0;
#pragma unroll
    for (int j = 0; j < 2; ++j) st_nt_f4(g + j * 128, l2[j]);
  }

  // ---- L4: attention over L1 rows (group == wave; slices 2g,2g+1) ----
  {
    float s8[8];
#pragma unroll
    for (int j = 0; j < 4; ++j) {
      const float sj = slice_sum(f4dot(l1[j], wv)) * scale;
      const float so = __shfl_xor(sj, 32, 64);
      if (h & 1) {
        s8[j] = so;
        s8[4 + j] = sj;
      } else {
        s8[j] = sj;
        s8[4 + j] = so;
      }
    }
    float wt[8];
    softmax_n<8>(s8, wt);
    const int base = (h & 1) * 4;
    float4 pa = f4mul(l1[0], wt[base]);
#pragma unroll
    for (int j = 1; j < 4; ++j) pa = f4fma(l1[j], wt[base + j], pa);
    pa.x += __shfl_xor(pa.x, 32, 64);
    pa.y += __shfl_xor(pa.y, 32, 64);
    pa.z += __shfl_xor(pa.z, 32, 64);
    pa.w += __shfl_xor(pa.w, 32, 64);
    if (!(h & 1)) st_nt_f4(out + O4 + (b * 4 + (h >> 1)) * 128 + c0, pa);
  }

  // ---- L5 & L6 scores -> LDS ----
  {
#pragma unroll
    for (int j = 0; j < 2; ++j) {
      const float sj = slice_sum(f4dot(l2[j], wv)) * scale;
      if (cg == j) ssc[h * 2 + j] = sj;  // block-local l2 row 2h+j
    }
    const float s6 = slice_sum(f4dot(l3, wv)) * scale;
    if (cg == 2) ssc[16 + h] = s6;  // block-local l3 row h
  }
  __syncthreads();

  // ---- L5/L6 partial weighted sums -> LDS ----
  {
    float wt5[8];
    softmax_n<8>(ssc + (h >> 2) * 8, wt5);  // group g5 = h>>2
    const int base = (h & 3) * 2;           // my l2 rows within group
    const float4 pa5 = f4fma(l2[1], wt5[base + 1], f4mul(l2[0], wt5[base]));
    *(float4*)(&pb5[h][c0]) = pa5;

    float wt6[8];
    softmax_n<8>(ssc + 16, wt6);
    *(float4*)(&pb6[h][c0]) = f4mul(l3, wt6[h]);
  }
  __syncthreads();

  // ---- combine + store L5 (256 vals), L6 (128 vals) ----
  {
    const int g = tid >> 7, c = tid & 127;
    const float v = pb5[g * 4 + 0][c] + pb5[g * 4 + 1][c] +
                    pb5[g * 4 + 2][c] + pb5[g * 4 + 3][c];
    st_nt_f1(out + O5 + (b * 2 + g) * 128 + c, v);
  }
  if (tid < 128) {
    float v = 0.f;
#pragma unroll
    for (int s = 0; s < 8; ++s) v += pb6[s][tid];
    st_nt_f1(out + O6 + b * 128 + tid, v);
  }
}

extern "C" void kernel_launch(void* const* d_in, const int* in_sizes, int n_in,
                              void* d_out, int out_size, void* d_ws,
                              size_t ws_size, hipStream_t stream) {
  const float* x0 = (const float*)d_in[0];
  const float* w = (const float*)d_in[1];
  float* out = (float*)d_out;
  const int n_leaves = in_sizes[0] / 128;  // 524288
  const int blocks = n_leaves / 64;        // 8192
  splat_fused<<<blocks, TPB, 0, stream>>>(x0, w, out);
}

// Round 7
// 86.406 us; speedup vs baseline: 1.2675x; 1.1169x over previous
//
#include <hip/hip_runtime.h>
#include <math.h>

// SplatCondenseNet fused tree pooling — round-4 structure + cross-subtree
// software pipelining in persistent blocks.
// Block = 256 threads; processes ITERS=4 consecutive 64-leaf subtrees.
// Thread layout: h = tid>>5 (slice 0..7) owns x rows 8h..8h+7 of the tile;
// cg = tid&31 owns columns 4cg..4cg+3 (float4 fragment).
//
// Pipeline: xr dies once l1 is formed -> next subtree's 8 loads are issued
// THERE, into the same registers (no extra pressure), and stay in flight
// through L1/L2/L4/L5/L6 compute + both barriers. Barriers are
// lgkmcnt(0)+s_barrier (NOT __syncthreads) so the global prefetch is not
// drained at the barrier (vmcnt stays outstanding; LDS fully ordered).
// Round-6 lesson: do NOT tighten launch_bounds past (256,2) — allocator
// needs ~96 unified regs; forcing less causes LDS scratch spill + conflicts.
// Round-5 lesson: keep 16B/lane float4 NT stores (8B NT stores amplified
// WRITE_SIZE 258->389 MB).
//
// Output layout (rows of 128 fp32, concat of layers 1..6):
//   L1 rows [0, 262144)  L2 [262144, 393216)  L3 [393216, 458752)
//   L4 [458752, 491520)  L5 [491520, 507904)  L6 [507904, 516096)

static constexpr size_t O1 = 0;
static constexpr size_t O2 = 262144ull * 128;
static constexpr size_t O3 = 393216ull * 128;
static constexpr size_t O4 = 458752ull * 128;
static constexpr size_t O5 = 491520ull * 128;
static constexpr size_t O6 = 507904ull * 128;

#define TPB 256
#define ITERS 4

typedef float f4v __attribute__((ext_vector_type(4)));

__device__ __forceinline__ float4 f4add(float4 a, float4 b) {
  return make_float4(a.x + b.x, a.y + b.y, a.z + b.z, a.w + b.w);
}
__device__ __forceinline__ float4 f4mul(float4 a, float s) {
  return make_float4(a.x * s, a.y * s, a.z * s, a.w * s);
}
__device__ __forceinline__ float4 f4fma(float4 a, float s, float4 c) {
  return make_float4(fmaf(a.x, s, c.x), fmaf(a.y, s, c.y), fmaf(a.z, s, c.z),
                     fmaf(a.w, s, c.w));
}
__device__ __forceinline__ float f4dot(float4 a, float4 b) {
  return a.x * b.x + a.y * b.y + a.z * b.z + a.w * b.w;
}
__device__ __forceinline__ void st_nt_f4(float* p, float4 v) {
  f4v t;
  t.x = v.x; t.y = v.y; t.z = v.z; t.w = v.w;
  __builtin_nontemporal_store(t, (f4v*)p);
}
__device__ __forceinline__ void st_nt_f1(float* p, float v) {
  __builtin_nontemporal_store(v, p);
}
// LDS-ordering barrier that does NOT drain vmcnt (keeps global prefetch
// in flight). "memory" clobbers pin ds ops on the correct side.
__device__ __forceinline__ void bar_lds() {
  asm volatile("s_waitcnt lgkmcnt(0)" ::: "memory");
  __builtin_amdgcn_s_barrier();
  asm volatile("" ::: "memory");
}
// sum across the 32-lane slice (lanes 0..31 or 32..63 of a wave)
__device__ __forceinline__ float slice_sum(float p) {
#pragma unroll
  for (int off = 16; off > 0; off >>= 1) p += __shfl_xor(p, off, 64);
  return p;
}

template <int N>
__device__ __forceinline__ void softmax_n(const float* s, float* wt) {
  float m = s[0];
#pragma unroll
  for (int i = 1; i < N; ++i) m = fmaxf(m, s[i]);
  float sum = 0.f;
#pragma unroll
  for (int i = 0; i < N; ++i) {
    wt[i] = __expf(s[i] - m);
    sum += wt[i];
  }
  const float inv = 1.f / sum;
#pragma unroll
  for (int i = 0; i < N; ++i) wt[i] *= inv;
}

__global__ __launch_bounds__(TPB, 2) void splat_fused(
    const float* __restrict__ x0, const float* __restrict__ w,
    float* __restrict__ out) {
  __shared__ float ssc[24];      // L5 scores [0..15], L6 scores [16..23]
  __shared__ float pb5[8][128];  // L5 per-slice partials
  __shared__ float pb6[8][128];  // L6 per-slice partials

  const int tid = threadIdx.x;
  const int h = tid >> 5;   // slice: owns x rows 8h..8h+7
  const int cg = tid & 31;  // column group
  const int c0 = cg << 2;
  const float scale = 0.08838834764831845f;  // 128^-0.5

  const float4 wv = *(const float4*)(w + c0);
  const size_t b0 = (size_t)blockIdx.x * ITERS;

  // ---- prologue: load subtree b0 (8 x float4, coalesced) ----
  float4 xr[8];
  {
    const float* xb = x0 + b0 * 8192 + (size_t)(h * 8) * 128 + c0;
#pragma unroll
    for (int r = 0; r < 8; ++r) xr[r] = *(const float4*)(xb + r * 128);
  }

#pragma unroll
  for (int it = 0; it < ITERS; ++it) {
    const size_t b = b0 + it;

    // ---- L3: attention over x rows 8h..8h+7 (group == slice) ----
    float4 l3;
    {
      float s3[8];
#pragma unroll
      for (int r = 0; r < 8; ++r) s3[r] = slice_sum(f4dot(xr[r], wv)) * scale;
      float wt[8];
      softmax_n<8>(s3, wt);
      l3 = f4mul(xr[0], wt[0]);
#pragma unroll
      for (int r = 1; r < 8; ++r) l3 = f4fma(xr[r], wt[r], l3);
    }

    // ---- L1: mean pairs (last use of xr) ----
    float4 l1[4];
#pragma unroll
    for (int j = 0; j < 4; ++j)
      l1[j] = f4mul(f4add(xr[2 * j], xr[2 * j + 1]), 0.5f);

    // ---- xr dead: prefetch next subtree into the same registers ----
    if (it + 1 < ITERS) {
      const float* xb = x0 + (b + 1) * 8192 + (size_t)(h * 8) * 128 + c0;
#pragma unroll
      for (int r = 0; r < 8; ++r) xr[r] = *(const float4*)(xb + r * 128);
    }

    st_nt_f4(out + O3 + (b * 8 + h) * 128 + c0, l3);
    {
      float* g = out + O1 + (b * 32 + h * 4) * 128 + c0;
#pragma unroll
      for (int j = 0; j < 4; ++j) st_nt_f4(g + j * 128, l1[j]);
    }

    // ---- L2: mean pairs of L1 ----
    float4 l2[2];
#pragma unroll
    for (int j = 0; j < 2; ++j)
      l2[j] = f4mul(f4add(l1[2 * j], l1[2 * j + 1]), 0.5f);
    {
      float* g = out + O2 + (b * 16 + h * 2) * 128 + c0;
#pragma unroll
      for (int j = 0; j < 2; ++j) st_nt_f4(g + j * 128, l2[j]);
    }

    // ---- L4: attention over L1 rows (group == wave; slices 2g,2g+1) ----
    {
      float s8[8];
#pragma unroll
      for (int j = 0; j < 4; ++j) {
        const float sj = slice_sum(f4dot(l1[j], wv)) * scale;
        const float so = __shfl_xor(sj, 32, 64);
        if (h & 1) {
          s8[j] = so;
          s8[4 + j] = sj;
        } else {
          s8[j] = sj;
          s8[4 + j] = so;
        }
      }
      float wt[8];
      softmax_n<8>(s8, wt);
      const int base = (h & 1) * 4;
      float4 pa = f4mul(l1[0], wt[base]);
#pragma unroll
      for (int j = 1; j < 4; ++j) pa = f4fma(l1[j], wt[base + j], pa);
      pa.x += __shfl_xor(pa.x, 32, 64);
      pa.y += __shfl_xor(pa.y, 32, 64);
      pa.z += __shfl_xor(pa.z, 32, 64);
      pa.w += __shfl_xor(pa.w, 32, 64);
      if (!(h & 1)) st_nt_f4(out + O4 + (b * 4 + (h >> 1)) * 128 + c0, pa);
    }

    // ---- L5 & L6 scores -> LDS ----
    {
#pragma unroll
      for (int j = 0; j < 2; ++j) {
        const float sj = slice_sum(f4dot(l2[j], wv)) * scale;
        if (cg == j) ssc[h * 2 + j] = sj;  // block-local l2 row 2h+j
      }
      const float s6 = slice_sum(f4dot(l3, wv)) * scale;
      if (cg == 2) ssc[16 + h] = s6;  // block-local l3 row h
    }
    bar_lds();

    // ---- L5/L6 partial weighted sums -> LDS ----
    {
      float wt5[8];
      softmax_n<8>(ssc + (h >> 2) * 8, wt5);  // group g5 = h>>2
      const int base = (h & 3) * 2;           // my l2 rows within group
      const float4 pa5 = f4fma(l2[1], wt5[base + 1], f4mul(l2[0], wt5[base]));
      *(float4*)(&pb5[h][c0]) = pa5;

      float wt6[8];
      softmax_n<8>(ssc + 16, wt6);
      *(float4*)(&pb6[h][c0]) = f4mul(l3, wt6[h]);
    }
    bar_lds();

    // ---- combine + store L5 (256 vals), L6 (128 vals) ----
    {
      const int g = tid >> 7, c = tid & 127;
      const float v = pb5[g * 4 + 0][c] + pb5[g * 4 + 1][c] +
                      pb5[g * 4 + 2][c] + pb5[g * 4 + 3][c];
      st_nt_f1(out + O5 + (b * 2 + g) * 128 + c, v);
    }
    if (tid < 128) {
      float v = 0.f;
#pragma unroll
      for (int s = 0; s < 8; ++s) v += pb6[s][tid];
      st_nt_f1(out + O6 + b * 128 + tid, v);
    }
    // Next iteration's ssc writes race only with this phase's pb reads
    // (disjoint LDS), so no extra barrier is needed here.
  }
}

extern "C" void kernel_launch(void* const* d_in, const int* in_sizes, int n_in,
                              void* d_out, int out_size, void* d_ws,
                              size_t ws_size, hipStream_t stream) {
  const float* x0 = (const float*)d_in[0];
  const float* w = (const float*)d_in[1];
  float* out = (float*)d_out;
  const int n_leaves = in_sizes[0] / 128;      // 524288
  const int n_sub = n_leaves / 64;             // 8192 subtrees
  const int blocks = n_sub / ITERS;            // 2048 persistent blocks
  splat_fused<<<blocks, TPB, 0, stream>>>(x0, w, out);
}